// Round 11
// baseline (194.824 us; speedup 1.0000x reference)
//
#include <hip/hip_runtime.h>
#include <hip/hip_bf16.h>
#include <cstdint>

// CIN layer chain: B=1024, F0=32, EMB=64, layer sizes 128/128/128.
// cur[b,k,e] = sum_{i,j} x[b,i,e] * h[b,j,e] * W[i*fi+j, k]
//
// R11: barrier-free K-loop (R10) + split-K(2) for TLP. R10 proved
// barriers/LDS-volume/conflicts are not binding: 46 us with all of them
// removed; ~550 cyc/chunk of exposed load latency at only 2 waves/SIMD.
// Now 4096 waves (batch x m-half x k-half), block = 4 waves (bb x ks),
// mh per block, grid 1024, 3 waves/SIMD, per-wave path halved. ks
// partials combined in a 2-barrier LDS epilogue.

typedef _Float16 half8  __attribute__((ext_vector_type(8)));
typedef _Float16 half4_ __attribute__((ext_vector_type(4)));
typedef _Float16 half2_ __attribute__((ext_vector_type(2)));
typedef float    f32x4  __attribute__((ext_vector_type(4)));
typedef unsigned short ushort4_ __attribute__((ext_vector_type(4)));

__device__ __forceinline__ void load_lds16(const void* g, void* l) {
    __builtin_amdgcn_global_load_lds(
        reinterpret_cast<const __attribute__((address_space(1))) unsigned*>(
            reinterpret_cast<uintptr_t>(g)),
        reinterpret_cast<__attribute__((address_space(3))) unsigned*>(
            reinterpret_cast<uintptr_t>(l)),
        16, 0, 0);
}

__device__ __forceinline__ unsigned short f16bits(float v) {
    return __builtin_bit_cast(unsigned short, (_Float16)v);
}

// Fused pack: W (fan_in,128) f32 -> chunked f16 Wt[c][m][kk] = W[c*32+kk][m].
__global__ void pack_w_all(const float* __restrict__ W0, _Float16* __restrict__ Wt0,
                           const float* __restrict__ W1, _Float16* __restrict__ Wt1,
                           const float* __restrict__ W2, _Float16* __restrict__ Wt2)
{
    __shared__ _Float16 ldsT[128 * 33];
    const int blk = blockIdx.x, t = threadIdx.x;
    const float* W;
    _Float16* Wt;
    int c;
    if (blk < 32)       { W = W0; Wt = Wt0; c = blk; }
    else if (blk < 96)  { W = W1; Wt = Wt1; c = blk - 32; }
    else                { W = W2; Wt = Wt2; c = blk - 96; }

    for (int p = t; p < 32 * 128; p += 256) {
        int kk = p >> 7, m = p & 127;
        ldsT[m * 33 + kk] = (_Float16)W[(size_t)(c * 32 + kk) * 128 + m];
    }
    __syncthreads();
    int m = t >> 1, kk0 = (t & 1) * 16;
    half8 v0, v1;
#pragma unroll
    for (int i = 0; i < 8; ++i) {
        v0[i] = ldsT[m * 33 + kk0 + i];
        v1[i] = ldsT[m * 33 + kk0 + 8 + i];
    }
    *(half8*)(Wt + (size_t)c * 4096 + t * 16)     = v0;
    *(half8*)(Wt + (size_t)c * 4096 + t * 16 + 8) = v1;
}

// One CIN layer. Grid 1024: blockIdx = (batch-pair << 1) | mh.
// Block = 256 thr = 4 waves: wave w -> ks=w&1, bb=w>>1.
// Wave tile M=64 (rows mh*64..) x N=64 (all e) x K-half. No in-loop barriers.
__global__ __launch_bounds__(256, 3)
void cin_layer(const float* __restrict__ x,         // (1024,32,64) f32
               const _Float16* __restrict__ h_in,   // (B,64,72) padded image, null => use x
               const _Float16* __restrict__ Wt,     // chunked [c][128][32] f16
               const float* __restrict__ bias,      // (128) f32
               _Float16* __restrict__ h_out,        // (B,64,72) padded image or null
               float* __restrict__ out,             // (1024,256) f32
               int ishift, int nchunks, int ph, int direct_m0, int out_base)
{
    __shared__ alignas(16) char smem[34816];
    _Float16* sH        = (_Float16*)smem;                 // 18 KB: hT [bb][e*ph + j]
    unsigned short* sXu = (unsigned short*)(smem + 18432); // 8 KB: x f16 bits [bb][i*64+e]
    // epilogue reuse (after post-loop barrier):
    float* bufA = (float*)smem;                  // 16 KB hidden-combine bb=0
    float* bufB = (float*)(smem + 16384);        // 16 KB hidden-combine bb=1
    float* sRed = (float*)(smem + 32768);        // 2 KB direct ks-partials

    const int t    = threadIdx.x;
    const int lane = t & 63;
    const int w    = t >> 6;
    const int ks   = w & 1;
    const int bb   = w >> 1;
    const int lr   = lane & 15;
    const int q    = lane >> 4;
    const int mh   = blockIdx.x & 1;
    const int b0   = (blockIdx.x >> 1) * 2;

    // ---- prologue staging (one barrier) ----
    {
        const float4* xv = (const float4*)(x + (size_t)b0 * 2048);
#pragma unroll
        for (int s = 0; s < 4; ++s) {
            int p4 = t + s * 256;          // 1024 float4 = 2 batches
            float4 v = xv[p4];
            ushort4_ d;
            d[0] = f16bits(v.x); d[1] = f16bits(v.y);
            d[2] = f16bits(v.z); d[3] = f16bits(v.w);
            *(ushort4_*)(sXu + p4 * 4) = d;
            if (!h_in) {
                // layer 0: hidden = x; build hT [e][j], pitch ph=40
                int bb2 = p4 >> 9, idx = (p4 & 511) * 4;
                int i = idx >> 6, e0 = idx & 63;
                _Float16* hb = sH + bb2 * (ph << 6);
                hb[(e0 + 0) * ph + i] = (_Float16)v.x;
                hb[(e0 + 1) * ph + i] = (_Float16)v.y;
                hb[(e0 + 2) * ph + i] = (_Float16)v.z;
                hb[(e0 + 3) * ph + i] = (_Float16)v.w;
            }
        }
    }
    if (h_in) {
        const char* src = (const char*)(h_in + (size_t)b0 * 4608);
        char* dst = (char*)sH;
        for (int off = t * 16; off < 18432; off += 4096)
            load_lds16(src + off, dst + off);
    }
    __syncthreads();

    // ---- barrier-free pipelined K-half loop ----
    const _Float16* aG       = Wt + (mh * 64 + lr) * 32 + q * 8;      // + c*4096 + mt*512
    const _Float16* hP       = sH + bb * (ph << 6) + lr * ph + q * 8; // + nt*16*ph + j0
    const unsigned short* xP = sXu + bb * 2048 + lr;                  // + i*64 + nt*16

    const int kh = nchunks >> 1;
    const int c0 = ks * kh;

    f32x4 acc[4][4] = {};
    half8 afA[4], afB[4], hvA[4], hvB[4];
    unsigned short xuA[4], xuB[4];

    // prefetch chunk c0 into A
    {
        const int i  = c0 >> ishift;
        const int j0 = (c0 - (i << ishift)) << 5;
        const _Float16* ag = aG + (size_t)c0 * 4096;
#pragma unroll
        for (int mt = 0; mt < 4; ++mt) afA[mt] = *(const half8*)(ag + mt * 512);
#pragma unroll
        for (int nt = 0; nt < 4; ++nt) {
            hvA[nt] = *(const half8*)(hP + nt * (ph << 4) + j0);
            xuA[nt] = xP[(i << 6) + (nt << 4)];
        }
    }

    for (int it = 0; it < kh; it += 2) {
        // prefetch chunk c0+it+1 into B (kh even)
        {
            const int c  = c0 + it + 1;
            const int i  = c >> ishift;
            const int j0 = (c - (i << ishift)) << 5;
            const _Float16* ag = aG + (size_t)c * 4096;
#pragma unroll
            for (int mt = 0; mt < 4; ++mt) afB[mt] = *(const half8*)(ag + mt * 512);
#pragma unroll
            for (int nt = 0; nt < 4; ++nt) {
                hvB[nt] = *(const half8*)(hP + nt * (ph << 4) + j0);
                xuB[nt] = xP[(i << 6) + (nt << 4)];
            }
        }
        // compute chunk c0+it from A
#pragma unroll
        for (int nt = 0; nt < 4; ++nt) {
            unsigned du = (unsigned)xuA[nt] * 0x10001u;
            half2_ xv2 = __builtin_bit_cast(half2_, du);
            half8 xv8 = __builtin_shufflevector(xv2, xv2, 0, 1, 0, 1, 0, 1, 0, 1);
            half8 bf = hvA[nt] * xv8;
#pragma unroll
            for (int mt = 0; mt < 4; ++mt)
                acc[mt][nt] = __builtin_amdgcn_mfma_f32_16x16x32_f16(
                    afA[mt], bf, acc[mt][nt], 0, 0, 0);
        }
        // prefetch chunk c0+it+2 into A
        if (it + 2 < kh) {
            const int c  = c0 + it + 2;
            const int i  = c >> ishift;
            const int j0 = (c - (i << ishift)) << 5;
            const _Float16* ag = aG + (size_t)c * 4096;
#pragma unroll
            for (int mt = 0; mt < 4; ++mt) afA[mt] = *(const half8*)(ag + mt * 512);
#pragma unroll
            for (int nt = 0; nt < 4; ++nt) {
                hvA[nt] = *(const half8*)(hP + nt * (ph << 4) + j0);
                xuA[nt] = xP[(i << 6) + (nt << 4)];
            }
        }
        // compute chunk c0+it+1 from B
#pragma unroll
        for (int nt = 0; nt < 4; ++nt) {
            unsigned du = (unsigned)xuB[nt] * 0x10001u;
            half2_ xv2 = __builtin_bit_cast(half2_, du);
            half8 xv8 = __builtin_shufflevector(xv2, xv2, 0, 1, 0, 1, 0, 1, 0, 1);
            half8 bf = hvB[nt] * xv8;
#pragma unroll
            for (int mt = 0; mt < 4; ++mt)
                acc[mt][nt] = __builtin_amdgcn_mfma_f32_16x16x32_f16(
                    afB[mt], bf, acc[mt][nt], 0, 0, 0);
        }
    }

    // ---- split-K combine epilogue (2 barriers total) ----
    __syncthreads();   // sH/sX now dead; safe to reuse smem

    const int batch = b0 + bb;
    const bool hidden_blk = (h_out != nullptr) && (mh == 0);

    if (hidden_blk) {
        if (ks == 1) {
            float* buf = bb ? bufB : bufA;
#pragma unroll
            for (int mt = 0; mt < 4; ++mt)
#pragma unroll
                for (int nt = 0; nt < 4; ++nt) {
                    int e = nt * 16 + lr;
#pragma unroll
                    for (int r = 0; r < 4; ++r) {
                        int m = mt * 16 + q * 4 + r;
                        buf[e * 64 + ((m + e) & 63)] = acc[mt][nt][r];
                    }
                }
        }
    } else {
        // direct rows: e-reduce per wave, stash ks-partials
#pragma unroll
        for (int mt = 0; mt < 4; ++mt) {
            f32x4 s = acc[mt][0] + acc[mt][1] + acc[mt][2] + acc[mt][3];
#pragma unroll
            for (int r = 0; r < 4; ++r) {
                float v = s[r];
                v += __shfl_xor(v, 1);
                v += __shfl_xor(v, 2);
                v += __shfl_xor(v, 4);
                v += __shfl_xor(v, 8);
                if (lr == 0)
                    sRed[(bb * 2 + ks) * 64 + (mt << 4) + q * 4 + r] = v;
            }
        }
    }
    __syncthreads();

    if (hidden_blk) {
        if (ks == 0) {
            const float* buf = bb ? bufB : bufA;
#pragma unroll
            for (int mt = 0; mt < 4; ++mt)
#pragma unroll
                for (int nt = 0; nt < 4; ++nt) {
                    int e = nt * 16 + lr;
                    int j = mt * 16 + q * 4;
                    half4_ vh;
#pragma unroll
                    for (int r = 0; r < 4; ++r) {
                        int m = j + r;
                        float v = acc[mt][nt][r] + buf[e * 64 + ((m + e) & 63)] + bias[m];
                        vh[r] = (_Float16)v;
                    }
                    *(half4_*)(h_out + (size_t)batch * 4608 + e * 72 + j) = vh;
                }
        }
    } else {
        // combine ks-partials: 2 bb x 64 rows
        for (int o = t; o < 128; o += 256) {
            int bb2 = o >> 6, ml = o & 63;
            int m = mh * 64 + ml;
            float v = sRed[(bb2 * 2 + 0) * 64 + ml]
                    + sRed[(bb2 * 2 + 1) * 64 + ml]
                    + 64.0f * bias[m];
            out[(size_t)(b0 + bb2) * 256 + out_base + (m - direct_m0)] = v;
        }
    }
}

extern "C" void kernel_launch(void* const* d_in, const int* in_sizes, int n_in,
                              void* d_out, int out_size, void* d_ws, size_t ws_size,
                              hipStream_t stream)
{
    const float* x  = (const float*)d_in[0];
    const float* W0 = (const float*)d_in[1];
    const float* b0 = (const float*)d_in[2];
    const float* W1 = (const float*)d_in[3];
    const float* b1 = (const float*)d_in[4];
    const float* W2 = (const float*)d_in[5];
    const float* b2 = (const float*)d_in[6];
    float* out = (float*)d_out;

    char* ws = (char*)d_ws;
    _Float16* Wt0 = (_Float16*)(ws + 0);                        // 256 KB
    _Float16* Wt1 = (_Float16*)(ws + 262144);                   // 512 KB
    _Float16* Wt2 = (_Float16*)(ws + 786432);                   // 512 KB
    _Float16* h1  = (_Float16*)(ws + 1310720);                  // 9 MB
    _Float16* h2  = (_Float16*)(ws + 1310720 + 9437184);        // 9 MB
    (void)in_sizes; (void)n_in; (void)out_size; (void)ws_size;

    hipLaunchKernelGGL(pack_w_all, dim3(160), dim3(256), 0, stream,
                       W0, Wt0, W1, Wt1, W2, Wt2);

    // layer 0: fi=32 (ishift=0), hidden=x, direct rows 64..127 -> out 0..63
    hipLaunchKernelGGL(cin_layer, dim3(1024), dim3(256), 0, stream,
                       x, (const _Float16*)nullptr, Wt0, b0, h1, out,
                       0, 32, 40, 64, 0);
    // layer 1: fi=64 (ishift=1), direct -> out 64..127
    hipLaunchKernelGGL(cin_layer, dim3(1024), dim3(256), 0, stream,
                       x, (const _Float16*)h1, Wt1, b1, h2, out,
                       1, 64, 72, 64, 64);
    // layer 2: fi=64, all rows direct -> out 128..255
    hipLaunchKernelGGL(cin_layer, dim3(1024), dim3(256), 0, stream,
                       x, (const _Float16*)h2, Wt2, b2, (_Float16*)nullptr, out,
                       1, 64, 72, 0, 128);
}

// Round 12
// 175.542 us; speedup vs baseline: 1.1098x; 1.1098x over previous
//
#include <hip/hip_runtime.h>
#include <hip/hip_bf16.h>
#include <cstdint>

// CIN layer chain: B=1024, F0=32, EMB=64, layer sizes 128/128/128.
// cur[b,k,e] = sum_{i,j} x[b,i,e] * h[b,j,e] * W[i*fi+j, k]
//
// R12: forced software pipeline. R3-R11 all ~46 us/layer because the
// compiler sinks prefetch loads to their use (VGPR_Count ~80 proves it:
// acc alone is 64), serializing every chunk on ~300-600 cyc of load
// latency at 2-4 waves/SIMD. No pipe is >30% busy (MFMA ~9%, L1 ~30%,
// LDS ~15%, VALU ~23%). Fix: 4 register buffer sets, unroll x4,
// prefetch distance 3 chunks, __builtin_amdgcn_sched_barrier(0) fences
// at region boundaries so loads stay issued ~350 cyc ahead of use.
// Structure otherwise = R10 (2048 waves, barrier-free K-loop, wave =
// batch x m-half, M=64 x N=64, af from global Wt, hv/xu from LDS).

typedef _Float16 half8  __attribute__((ext_vector_type(8)));
typedef _Float16 half4_ __attribute__((ext_vector_type(4)));
typedef _Float16 half2_ __attribute__((ext_vector_type(2)));
typedef float    f32x4  __attribute__((ext_vector_type(4)));
typedef unsigned short ushort4_ __attribute__((ext_vector_type(4)));

__device__ __forceinline__ void load_lds16(const void* g, void* l) {
    __builtin_amdgcn_global_load_lds(
        reinterpret_cast<const __attribute__((address_space(1))) unsigned*>(
            reinterpret_cast<uintptr_t>(g)),
        reinterpret_cast<__attribute__((address_space(3))) unsigned*>(
            reinterpret_cast<uintptr_t>(l)),
        16, 0, 0);
}

__device__ __forceinline__ unsigned short f16bits(float v) {
    return __builtin_bit_cast(unsigned short, (_Float16)v);
}

// Fused pack: W (fan_in,128) f32 -> chunked f16 Wt[c][m][kk] = W[c*32+kk][m].
__global__ void pack_w_all(const float* __restrict__ W0, _Float16* __restrict__ Wt0,
                           const float* __restrict__ W1, _Float16* __restrict__ Wt1,
                           const float* __restrict__ W2, _Float16* __restrict__ Wt2)
{
    __shared__ _Float16 ldsT[128 * 33];
    const int blk = blockIdx.x, t = threadIdx.x;
    const float* W;
    _Float16* Wt;
    int c;
    if (blk < 32)       { W = W0; Wt = Wt0; c = blk; }
    else if (blk < 96)  { W = W1; Wt = Wt1; c = blk - 32; }
    else                { W = W2; Wt = Wt2; c = blk - 96; }

    for (int p = t; p < 32 * 128; p += 256) {
        int kk = p >> 7, m = p & 127;
        ldsT[m * 33 + kk] = (_Float16)W[(size_t)(c * 32 + kk) * 128 + m];
    }
    __syncthreads();
    int m = t >> 1, kk0 = (t & 1) * 16;
    half8 v0, v1;
#pragma unroll
    for (int i = 0; i < 8; ++i) {
        v0[i] = ldsT[m * 33 + kk0 + i];
        v1[i] = ldsT[m * 33 + kk0 + 8 + i];
    }
    *(half8*)(Wt + (size_t)c * 4096 + t * 16)     = v0;
    *(half8*)(Wt + (size_t)c * 4096 + t * 16 + 8) = v1;
}

// One CIN layer. Block = 2 batches, 256 threads (4 waves).
// Wave w: mh=w&1 (m-half), bb=w>>1 (batch). Wave tile M=64 x N=64, full K.
__global__ __launch_bounds__(256, 2)
void cin_layer(const float* __restrict__ x,         // (1024,32,64) f32
               const _Float16* __restrict__ h_in,   // (B,64,72) padded image, null => use x
               const _Float16* __restrict__ Wt,     // chunked [c][128][32] f16
               const float* __restrict__ bias,      // (128) f32
               _Float16* __restrict__ h_out,        // (B,64,72) padded image or null
               float* __restrict__ out,             // (1024,256) f32
               int ishift, int nchunks, int ph, int direct_m0, int out_base)
{
    __shared__ alignas(16) char smem[26624];
    _Float16* sH        = (_Float16*)smem;                 // 18 KB: hT [bb][e*ph + j]
    unsigned short* sXu = (unsigned short*)(smem + 18432); // 8 KB: x f16 bits [bb][i*64+e]

    const int t    = threadIdx.x;
    const int lane = t & 63;
    const int w    = t >> 6;
    const int mh   = w & 1;
    const int bb   = w >> 1;
    const int lr   = lane & 15;
    const int q    = lane >> 4;
    const int b0   = blockIdx.x * 2;

    // ---- prologue staging (one barrier total) ----
    {
        const float4* xv = (const float4*)(x + (size_t)b0 * 2048);
#pragma unroll
        for (int s = 0; s < 4; ++s) {
            int p4 = t + s * 256;          // 1024 float4 = 2 batches
            float4 v = xv[p4];
            ushort4_ d;
            d[0] = f16bits(v.x); d[1] = f16bits(v.y);
            d[2] = f16bits(v.z); d[3] = f16bits(v.w);
            *(ushort4_*)(sXu + p4 * 4) = d;
            if (!h_in) {
                // layer 0: hidden = x; build hT [e][j], pitch ph=40
                int bb2 = p4 >> 9, idx = (p4 & 511) * 4;
                int i = idx >> 6, e0 = idx & 63;
                _Float16* hb = sH + bb2 * (ph << 6);
                hb[(e0 + 0) * ph + i] = (_Float16)v.x;
                hb[(e0 + 1) * ph + i] = (_Float16)v.y;
                hb[(e0 + 2) * ph + i] = (_Float16)v.z;
                hb[(e0 + 3) * ph + i] = (_Float16)v.w;
            }
        }
    }
    if (h_in) {
        const char* src = (const char*)(h_in + (size_t)b0 * 4608);
        char* dst = (char*)sH;
        for (int off = t * 16; off < 18432; off += 4096)
            load_lds16(src + off, dst + off);
    }
    __syncthreads();   // the ONLY block barrier

    // ---- forced-pipeline K-loop (4 sets, distance-3 prefetch) ----
    const _Float16* aG       = Wt + (mh * 64 + lr) * 32 + q * 8;      // + c*4096 + mt*512
    const _Float16* hP       = sH + bb * (ph << 6) + lr * ph + q * 8; // + nt*16*ph + j0
    const unsigned short* xP = sXu + bb * 2048 + lr;                  // + i*64 + nt*16

    f32x4 acc[4][4] = {};
    half8 af[4][4];
    half8 hv[4][4];
    unsigned short xu[4][4];

    auto PF = [&](int s, int c) {
        const int i  = c >> ishift;
        const int j0 = (c - (i << ishift)) << 5;
        const _Float16* ag = aG + (size_t)c * 4096;
#pragma unroll
        for (int mt = 0; mt < 4; ++mt)
            af[s][mt] = *(const half8*)(ag + mt * 512);
#pragma unroll
        for (int nt = 0; nt < 4; ++nt) {
            hv[s][nt] = *(const half8*)(hP + nt * (ph << 4) + j0);
            xu[s][nt] = xP[(i << 6) + (nt << 4)];
        }
    };
    auto CP = [&](int s) {
#pragma unroll
        for (int nt = 0; nt < 4; ++nt) {
            unsigned du = (unsigned)xu[s][nt] * 0x10001u;
            half2_ xv2 = __builtin_bit_cast(half2_, du);
            half8 xv8 = __builtin_shufflevector(xv2, xv2, 0, 1, 0, 1, 0, 1, 0, 1);
            half8 bf = hv[s][nt] * xv8;
#pragma unroll
            for (int mt = 0; mt < 4; ++mt)
                acc[mt][nt] = __builtin_amdgcn_mfma_f32_16x16x32_f16(
                    af[s][mt], bf, acc[mt][nt], 0, 0, 0);
        }
    };

    PF(0, 0); PF(1, 1); PF(2, 2); PF(3, 3);
    __builtin_amdgcn_sched_barrier(0);

    for (int it = 0; it < nchunks; it += 4) {
        CP(0);
        __builtin_amdgcn_sched_barrier(0);
        if (it + 4 < nchunks) PF(0, it + 4);
        __builtin_amdgcn_sched_barrier(0);
        CP(1);
        __builtin_amdgcn_sched_barrier(0);
        if (it + 5 < nchunks) PF(1, it + 5);
        __builtin_amdgcn_sched_barrier(0);
        CP(2);
        __builtin_amdgcn_sched_barrier(0);
        if (it + 6 < nchunks) PF(2, it + 6);
        __builtin_amdgcn_sched_barrier(0);
        CP(3);
        __builtin_amdgcn_sched_barrier(0);
        if (it + 7 < nchunks) PF(3, it + 7);
        __builtin_amdgcn_sched_barrier(0);
    }

    // ---- epilogue (wave-private, no cross-wave combine) ----
    const int batch = b0 + bb;

    if (h_out != nullptr && mh == 0) {
        // hidden rows 0..63: acc + bias -> padded f16 image [e*72 + j]
#pragma unroll
        for (int mt = 0; mt < 4; ++mt)
#pragma unroll
            for (int nt = 0; nt < 4; ++nt) {
                int e = nt * 16 + lr;
                int j = mt * 16 + q * 4;
                half4_ vh;
#pragma unroll
                for (int r = 0; r < 4; ++r)
                    vh[r] = (_Float16)(acc[mt][nt][r] + bias[j + r]);
                *(half4_*)(h_out + (size_t)batch * 4608 + e * 72 + j) = vh;
            }
    }
    // direct rows (global m = mh*64 + mt*16 + q*4 + r >= direct_m0)
#pragma unroll
    for (int mt = 0; mt < 4; ++mt) {
        if (mh * 64 + (mt << 4) >= direct_m0) {
            f32x4 s = acc[mt][0] + acc[mt][1] + acc[mt][2] + acc[mt][3];
#pragma unroll
            for (int r = 0; r < 4; ++r) {
                float v = s[r];
                v += __shfl_xor(v, 1);
                v += __shfl_xor(v, 2);
                v += __shfl_xor(v, 4);
                v += __shfl_xor(v, 8);
                if (lr == 0) {
                    int m = mh * 64 + (mt << 4) + q * 4 + r;
                    out[(size_t)batch * 256 + out_base + (m - direct_m0)]
                        = v + 64.0f * bias[m];
                }
            }
        }
    }
}

extern "C" void kernel_launch(void* const* d_in, const int* in_sizes, int n_in,
                              void* d_out, int out_size, void* d_ws, size_t ws_size,
                              hipStream_t stream)
{
    const float* x  = (const float*)d_in[0];
    const float* W0 = (const float*)d_in[1];
    const float* b0 = (const float*)d_in[2];
    const float* W1 = (const float*)d_in[3];
    const float* b1 = (const float*)d_in[4];
    const float* W2 = (const float*)d_in[5];
    const float* b2 = (const float*)d_in[6];
    float* out = (float*)d_out;

    char* ws = (char*)d_ws;
    _Float16* Wt0 = (_Float16*)(ws + 0);                        // 256 KB
    _Float16* Wt1 = (_Float16*)(ws + 262144);                   // 512 KB
    _Float16* Wt2 = (_Float16*)(ws + 786432);                   // 512 KB
    _Float16* h1  = (_Float16*)(ws + 1310720);                  // 9 MB
    _Float16* h2  = (_Float16*)(ws + 1310720 + 9437184);        // 9 MB
    (void)in_sizes; (void)n_in; (void)out_size; (void)ws_size;

    hipLaunchKernelGGL(pack_w_all, dim3(160), dim3(256), 0, stream,
                       W0, Wt0, W1, Wt1, W2, Wt2);

    // layer 0: fi=32 (ishift=0), hidden=x, direct rows 64..127 -> out 0..63
    hipLaunchKernelGGL(cin_layer, dim3(512), dim3(256), 0, stream,
                       x, (const _Float16*)nullptr, Wt0, b0, h1, out,
                       0, 32, 40, 64, 0);
    // layer 1: fi=64 (ishift=1), direct -> out 64..127
    hipLaunchKernelGGL(cin_layer, dim3(512), dim3(256), 0, stream,
                       x, (const _Float16*)h1, Wt1, b1, h2, out,
                       1, 64, 72, 64, 64);
    // layer 2: fi=64, all rows direct -> out 128..255
    hipLaunchKernelGGL(cin_layer, dim3(512), dim3(256), 0, stream,
                       x, (const _Float16*)h2, Wt2, b2, (_Float16*)nullptr, out,
                       1, 64, 72, 0, 128);
}

// Round 13
// 158.459 us; speedup vs baseline: 1.2295x; 1.1078x over previous
//
#include <hip/hip_runtime.h>
#include <hip/hip_bf16.h>
#include <cstdint>

// CIN layer chain: B=1024, F0=32, EMB=64, layer sizes 128/128/128.
// cur[b,k,e] = sum_{i,j} x[b,i,e] * h[b,j,e] * W[i*fi+j, k]
//
// R13: FUSED 3-layer kernel. R3-R12 established the per-layer K-loop is
// pinned at ~46 us (= 36% of MFMA ubench peak, the documented m97
// plateau; pipe sums MFMA 40k + LDS 36k + L1 33k + VALU 20k cyc/CU =
// measured 110k, non-overlapping at 2 waves/SIMD). But dispatches sum to
// ~122 us vs 175 total: ~50 us is launch/gap overhead. The chain is
// per-batch independent (h1[b] <- x[b]), so all 3 layers fuse into one
// kernel: hidden images ping-pong between two LDS slots (slotA/slotB),
// 2 inter-phase barriers, no h1/h2 HBM round-trip, one launch.
// K-loop itself = R10's barrier-free 2-deep register pipeline.

typedef _Float16 half8  __attribute__((ext_vector_type(8)));
typedef _Float16 half4_ __attribute__((ext_vector_type(4)));
typedef _Float16 half2_ __attribute__((ext_vector_type(2)));
typedef float    f32x4  __attribute__((ext_vector_type(4)));
typedef unsigned short ushort4_ __attribute__((ext_vector_type(4)));

__device__ __forceinline__ unsigned short f16bits(float v) {
    return __builtin_bit_cast(unsigned short, (_Float16)v);
}

// Fused pack: W (fan_in,128) f32 -> chunked f16 Wt[c][m][kk] = W[c*32+kk][m].
__global__ void pack_w_all(const float* __restrict__ W0, _Float16* __restrict__ Wt0,
                           const float* __restrict__ W1, _Float16* __restrict__ Wt1,
                           const float* __restrict__ W2, _Float16* __restrict__ Wt2)
{
    __shared__ _Float16 ldsT[128 * 33];
    const int blk = blockIdx.x, t = threadIdx.x;
    const float* W;
    _Float16* Wt;
    int c;
    if (blk < 32)       { W = W0; Wt = Wt0; c = blk; }
    else if (blk < 96)  { W = W1; Wt = Wt1; c = blk - 32; }
    else                { W = W2; Wt = Wt2; c = blk - 96; }

    for (int p = t; p < 32 * 128; p += 256) {
        int kk = p >> 7, m = p & 127;
        ldsT[m * 33 + kk] = (_Float16)W[(size_t)(c * 32 + kk) * 128 + m];
    }
    __syncthreads();
    int m = t >> 1, kk0 = (t & 1) * 16;
    half8 v0, v1;
#pragma unroll
    for (int i = 0; i < 8; ++i) {
        v0[i] = ldsT[m * 33 + kk0 + i];
        v1[i] = ldsT[m * 33 + kk0 + 8 + i];
    }
    *(half8*)(Wt + (size_t)c * 4096 + t * 16)     = v0;
    *(half8*)(Wt + (size_t)c * 4096 + t * 16 + 8) = v1;
}

// Fused 3-layer CIN. Block = 2 batches, 256 threads (4 waves).
// Wave w: mh=w&1 (m-half), bb=w>>1 (batch). Wave tile M=64 x N=64 per phase.
__global__ __launch_bounds__(256, 2)
void cin_fused(const float* __restrict__ x,          // (1024,32,64) f32
               const _Float16* __restrict__ Wt0,     // chunked [32][128][32]
               const _Float16* __restrict__ Wt1,     // chunked [64][128][32]
               const _Float16* __restrict__ Wt2,     // chunked [64][128][32]
               const float* __restrict__ bs0,
               const float* __restrict__ bs1,
               const float* __restrict__ bs2,
               float* __restrict__ out)              // (1024,256) f32
{
    __shared__ alignas(16) char smem[45056];               // 44 KB
    _Float16* slotA     = (_Float16*)smem;                 // 18 KB hT (pitch 40/72)
    _Float16* slotB     = (_Float16*)(smem + 18432);       // 18 KB hT (pitch 72)
    unsigned short* sXu = (unsigned short*)(smem + 36864); // 8 KB x f16 bits

    const int t    = threadIdx.x;
    const int lane = t & 63;
    const int w    = t >> 6;
    const int mh   = w & 1;
    const int bb   = w >> 1;
    const int lr   = lane & 15;
    const int q    = lane >> 4;
    const int b0   = blockIdx.x * 2;
    const int batch = b0 + bb;

    // ---- prologue: x -> sXu ; hT0 (pitch 40) -> slotA ----
    {
        const float4* xv = (const float4*)(x + (size_t)b0 * 2048);
#pragma unroll
        for (int s = 0; s < 4; ++s) {
            int p4 = t + s * 256;          // 1024 float4 = 2 batches
            float4 v = xv[p4];
            ushort4_ d;
            d[0] = f16bits(v.x); d[1] = f16bits(v.y);
            d[2] = f16bits(v.z); d[3] = f16bits(v.w);
            *(ushort4_*)(sXu + p4 * 4) = d;
            int bb2 = p4 >> 9, idx = (p4 & 511) * 4;
            int i = idx >> 6, e0 = idx & 63;
            _Float16* hb = slotA + bb2 * 2560;   // pitch 40
            hb[(e0 + 0) * 40 + i] = (_Float16)v.x;
            hb[(e0 + 1) * 40 + i] = (_Float16)v.y;
            hb[(e0 + 2) * 40 + i] = (_Float16)v.z;
            hb[(e0 + 3) * 40 + i] = (_Float16)v.w;
        }
    }
    __syncthreads();

    const unsigned short* xP = sXu + bb * 2048 + lr;   // + i*64 + nt*16

    f32x4 acc[4][4];

    // ---- K-loop: R10 barrier-free 2-deep register pipeline ----
    auto kloop = [&](const _Float16* WtL, int nch, int ish,
                     const _Float16* hbase, int ph) {
#pragma unroll
        for (int mt = 0; mt < 4; ++mt)
#pragma unroll
            for (int nt = 0; nt < 4; ++nt)
                acc[mt][nt] = f32x4{0.0f, 0.0f, 0.0f, 0.0f};

        const _Float16* aG = WtL + (mh * 64 + lr) * 32 + q * 8;     // + c*4096 + mt*512
        const _Float16* hP = hbase + bb * (ph << 6) + lr * ph + q * 8;

        half8 afA[4], afB[4], hvA[4], hvB[4];
        unsigned short xuA[4], xuB[4];

        // prefetch chunk 0 (i=0, j0=0)
#pragma unroll
        for (int mt = 0; mt < 4; ++mt) afA[mt] = *(const half8*)(aG + mt * 512);
#pragma unroll
        for (int nt = 0; nt < 4; ++nt) {
            hvA[nt] = *(const half8*)(hP + nt * (ph << 4));
            xuA[nt] = xP[nt << 4];
        }

        for (int it = 0; it < nch; it += 2) {
            {   // prefetch chunk it+1 into B (nch even)
                const int c  = it + 1;
                const int i  = c >> ish;
                const int j0 = (c - (i << ish)) << 5;
                const _Float16* ag = aG + (size_t)c * 4096;
#pragma unroll
                for (int mt = 0; mt < 4; ++mt) afB[mt] = *(const half8*)(ag + mt * 512);
#pragma unroll
                for (int nt = 0; nt < 4; ++nt) {
                    hvB[nt] = *(const half8*)(hP + nt * (ph << 4) + j0);
                    xuB[nt] = xP[(i << 6) + (nt << 4)];
                }
            }
            // compute chunk it from A regs
#pragma unroll
            for (int nt = 0; nt < 4; ++nt) {
                unsigned du = (unsigned)xuA[nt] * 0x10001u;
                half2_ xv2 = __builtin_bit_cast(half2_, du);
                half8 xv8 = __builtin_shufflevector(xv2, xv2, 0, 1, 0, 1, 0, 1, 0, 1);
                half8 bf = hvA[nt] * xv8;
#pragma unroll
                for (int mt = 0; mt < 4; ++mt)
                    acc[mt][nt] = __builtin_amdgcn_mfma_f32_16x16x32_f16(
                        afA[mt], bf, acc[mt][nt], 0, 0, 0);
            }
            // prefetch chunk it+2 into A
            if (it + 2 < nch) {
                const int c  = it + 2;
                const int i  = c >> ish;
                const int j0 = (c - (i << ish)) << 5;
                const _Float16* ag = aG + (size_t)c * 4096;
#pragma unroll
                for (int mt = 0; mt < 4; ++mt) afA[mt] = *(const half8*)(ag + mt * 512);
#pragma unroll
                for (int nt = 0; nt < 4; ++nt) {
                    hvA[nt] = *(const half8*)(hP + nt * (ph << 4) + j0);
                    xuA[nt] = xP[(i << 6) + (nt << 4)];
                }
            }
            // compute chunk it+1 from B regs
#pragma unroll
            for (int nt = 0; nt < 4; ++nt) {
                unsigned du = (unsigned)xuB[nt] * 0x10001u;
                half2_ xv2 = __builtin_bit_cast(half2_, du);
                half8 xv8 = __builtin_shufflevector(xv2, xv2, 0, 1, 0, 1, 0, 1, 0, 1);
                half8 bf = hvB[nt] * xv8;
#pragma unroll
                for (int mt = 0; mt < 4; ++mt)
                    acc[mt][nt] = __builtin_amdgcn_mfma_f32_16x16x32_f16(
                        afB[mt], bf, acc[mt][nt], 0, 0, 0);
            }
        }
    };

    // hidden epilogue (mh==0 waves): rows 0..63 + bias -> LDS slot, pitch 72
    auto hid_epi = [&](const float* bias_, _Float16* slot) {
#pragma unroll
        for (int mt = 0; mt < 4; ++mt)
#pragma unroll
            for (int nt = 0; nt < 4; ++nt) {
                int e = nt * 16 + lr;
                int j = mt * 16 + q * 4;
                half4_ vh;
#pragma unroll
                for (int r = 0; r < 4; ++r)
                    vh[r] = (_Float16)(acc[mt][nt][r] + bias_[j + r]);
                *(half4_*)(slot + bb * 4608 + e * 72 + j) = vh;
            }
    };

    // direct epilogue: rows m >= dm0, e-sum + 64*bias -> out
    auto dir_epi = [&](const float* bias_, int dm0, int ob) {
#pragma unroll
        for (int mt = 0; mt < 4; ++mt) {
            if (mh * 64 + (mt << 4) >= dm0) {
                f32x4 s = acc[mt][0] + acc[mt][1] + acc[mt][2] + acc[mt][3];
#pragma unroll
                for (int r = 0; r < 4; ++r) {
                    float v = s[r];
                    v += __shfl_xor(v, 1);
                    v += __shfl_xor(v, 2);
                    v += __shfl_xor(v, 4);
                    v += __shfl_xor(v, 8);
                    if (lr == 0) {
                        int m = mh * 64 + (mt << 4) + q * 4 + r;
                        out[(size_t)batch * 256 + ob + (m - dm0)]
                            = v + 64.0f * bias_[m];
                    }
                }
            }
        }
    };

    // ---- layer 0: h = x (slotA pitch 40), K=1024 -> hT1 (slotB) + out 0..63
    kloop(Wt0, 32, 0, slotA, 40);
    if (mh == 0) hid_epi(bs0, slotB);
    else         dir_epi(bs0, 64, 0);
    __syncthreads();

    // ---- layer 1: h = hT1 (slotB pitch 72), K=2048 -> hT2 (slotA) + out 64..127
    kloop(Wt1, 64, 1, slotB, 72);
    if (mh == 0) hid_epi(bs1, slotA);
    else         dir_epi(bs1, 64, 64);
    __syncthreads();

    // ---- layer 2: h = hT2 (slotA pitch 72), all rows direct -> out 128..255
    kloop(Wt2, 64, 1, slotA, 72);
    dir_epi(bs2, 0, 128);
}

extern "C" void kernel_launch(void* const* d_in, const int* in_sizes, int n_in,
                              void* d_out, int out_size, void* d_ws, size_t ws_size,
                              hipStream_t stream)
{
    const float* x  = (const float*)d_in[0];
    const float* W0 = (const float*)d_in[1];
    const float* b0 = (const float*)d_in[2];
    const float* W1 = (const float*)d_in[3];
    const float* b1 = (const float*)d_in[4];
    const float* W2 = (const float*)d_in[5];
    const float* b2 = (const float*)d_in[6];
    float* out = (float*)d_out;

    char* ws = (char*)d_ws;
    _Float16* Wt0 = (_Float16*)(ws + 0);          // 256 KB
    _Float16* Wt1 = (_Float16*)(ws + 262144);     // 512 KB
    _Float16* Wt2 = (_Float16*)(ws + 786432);     // 512 KB
    (void)in_sizes; (void)n_in; (void)out_size; (void)ws_size;

    hipLaunchKernelGGL(pack_w_all, dim3(160), dim3(256), 0, stream,
                       W0, Wt0, W1, Wt1, W2, Wt2);

    hipLaunchKernelGGL(cin_fused, dim3(512), dim3(256), 0, stream,
                       x, Wt0, Wt1, Wt2, b0, b1, b2, out);
}

// Round 14
// 120.906 us; speedup vs baseline: 1.6114x; 1.3106x over previous
//
#include <hip/hip_runtime.h>
#include <hip/hip_bf16.h>
#include <cstdint>

// CIN chain: B=1024, F0=32, EMB=64, layers 128/128/128.
// cur[b,k,e] = sum_{i,j} x[b,i,e]*h[b,j,e]*W[i*fi+j,k]
//
// R14: ALGEBRAIC RESTRUCTURE. R3-R13: nine K-loop structures all pin at
// ~839 TF = the documented m97 HIP-source plateau. So cut FLOPs instead:
// direct outputs need only sum_e cur -> out_dir[b,k] = <W[:,k], S[b,:]>
// with S_l[b,i,j] = sum_e x*h (tiny per-batch Gram via MFMA). Per-e MFMA
// work remains only for hidden halves (M=64, layers 0,1); layer 2's
// K-loop vanishes. 84 -> 27 GFLOP; per-wave chunk-steps 160 -> 48.
// Kernels: pack -> cin_fused (hidden M=64 split-K + S0/S1/S2 -> ws) ->
// cin_direct (GEMM S_l @ Wd_l, Wd = direct rows of packed Wt).

typedef _Float16 half8  __attribute__((ext_vector_type(8)));
typedef _Float16 half4_ __attribute__((ext_vector_type(4)));
typedef _Float16 half2_ __attribute__((ext_vector_type(2)));
typedef float    f32x4  __attribute__((ext_vector_type(4)));

__device__ __forceinline__ unsigned short f16bits(float v) {
    return __builtin_bit_cast(unsigned short, (_Float16)v);
}

// Pack W (fan_in,128) f32 -> chunked f16 Wt[c][m][kk] = W[c*32+kk][m].
__global__ void pack_w_all(const float* __restrict__ W0, _Float16* __restrict__ Wt0,
                           const float* __restrict__ W1, _Float16* __restrict__ Wt1,
                           const float* __restrict__ W2, _Float16* __restrict__ Wt2)
{
    __shared__ _Float16 ldsT[128 * 33];
    const int blk = blockIdx.x, t = threadIdx.x;
    const float* W;
    _Float16* Wt;
    int c;
    if (blk < 32)       { W = W0; Wt = Wt0; c = blk; }
    else if (blk < 96)  { W = W1; Wt = Wt1; c = blk - 32; }
    else                { W = W2; Wt = Wt2; c = blk - 96; }

    for (int p = t; p < 32 * 128; p += 256) {
        int kk = p >> 7, m = p & 127;
        ldsT[m * 33 + kk] = (_Float16)W[(size_t)(c * 32 + kk) * 128 + m];
    }
    __syncthreads();
    int m = t >> 1, kk0 = (t & 1) * 16;
    half8 v0, v1;
#pragma unroll
    for (int i = 0; i < 8; ++i) {
        v0[i] = ldsT[m * 33 + kk0 + i];
        v1[i] = ldsT[m * 33 + kk0 + 8 + i];
    }
    *(half8*)(Wt + (size_t)c * 4096 + t * 16)     = v0;
    *(half8*)(Wt + (size_t)c * 4096 + t * 16 + 8) = v1;
}

// Fused hidden+S kernel. Block = 2 batches, 256 thr = 4 waves (bb x ks).
__global__ __launch_bounds__(256, 2)
void cin_fused(const float* __restrict__ x,          // (1024,32,64) f32
               const _Float16* __restrict__ Wt0,
               const _Float16* __restrict__ Wt1,
               const float* __restrict__ bs0,
               const float* __restrict__ bs1,
               _Float16* __restrict__ S0,             // (1024,1024)
               _Float16* __restrict__ S1,             // (1024,2048)
               _Float16* __restrict__ S2)             // (1024,2048)
{
    __shared__ alignas(16) char smem[61440];
    _Float16* slotA = (_Float16*)smem;                 // 18 KB: hT0 / hJ images
    _Float16* slotB = (_Float16*)(smem + 18432);       // 18 KB: hT1 image
    _Float16* sX    = (_Float16*)(smem + 36864);       // 8 KB: x [bb][i*64+e]
    _Float16* xchg  = (_Float16*)(smem + 45056);       // 16 KB: [bb][lane][64]

    const int t = threadIdx.x, lane = t & 63, w = t >> 6;
    const int ks = w & 1, bb = w >> 1;
    const int lr = lane & 15, q = lane >> 4;
    const int b0 = blockIdx.x * 2;
    const int batch = b0 + bb;

    // prologue: x -> sX [i][e]; hT0 [e][i] pitch 40 -> slotA
    {
        const float4* xv = (const float4*)(x + (size_t)b0 * 2048);
#pragma unroll
        for (int s = 0; s < 4; ++s) {
            int p4 = t + s * 256;
            float4 v = xv[p4];
            int bb2 = p4 >> 9, idx = (p4 & 511) * 4;
            int i = idx >> 6, e0 = idx & 63;
            _Float16 h0 = (_Float16)v.x, h1 = (_Float16)v.y;
            _Float16 h2 = (_Float16)v.z, h3 = (_Float16)v.w;
            half4_ pk = {h0, h1, h2, h3};
            *(half4_*)(sX + bb2 * 2048 + i * 64 + e0) = pk;
            _Float16* hb = slotA + bb2 * 2560;
            hb[(e0 + 0) * 40 + i] = h0;
            hb[(e0 + 1) * 40 + i] = h1;
            hb[(e0 + 2) * 40 + i] = h2;
            hb[(e0 + 3) * 40 + i] = h3;
        }
    }
    __syncthreads();                                   // B0

    f32x4 acc[4][4];

    // barrier-free 2-deep pipelined K-loop, hidden rows only (M=64)
    auto kloop = [&](const _Float16* WtL, int cBeg, int cEnd, int ish,
                     const _Float16* hbase, int ph) {
#pragma unroll
        for (int mt = 0; mt < 4; ++mt)
#pragma unroll
            for (int nt = 0; nt < 4; ++nt)
                acc[mt][nt] = f32x4{0.0f, 0.0f, 0.0f, 0.0f};
        const _Float16* aG = WtL + lr * 32 + q * 8;
        const _Float16* hP = hbase + bb * (ph << 6) + lr * ph + q * 8;
        const _Float16* xP = sX + bb * 2048 + lr;
        half8 afA[4], afB[4], hvA[4], hvB[4];
        _Float16 xsA[4], xsB[4];
        auto pf = [&](half8* af, half8* hv, _Float16* xs, int c) {
            const int i  = c >> ish;
            const int j0 = (c - (i << ish)) << 5;
            const _Float16* ag = aG + (size_t)c * 4096;
#pragma unroll
            for (int mt = 0; mt < 4; ++mt) af[mt] = *(const half8*)(ag + mt * 512);
#pragma unroll
            for (int nt = 0; nt < 4; ++nt) {
                hv[nt] = *(const half8*)(hP + nt * (ph << 4) + j0);
                xs[nt] = xP[(i << 6) + (nt << 4)];
            }
        };
        auto cp = [&](half8* af, half8* hv, _Float16* xs) {
#pragma unroll
            for (int nt = 0; nt < 4; ++nt) {
                half2_ xv2 = {xs[nt], xs[nt]};
                half8 xv8 = __builtin_shufflevector(xv2, xv2, 0, 1, 0, 1, 0, 1, 0, 1);
                half8 bf = hv[nt] * xv8;
#pragma unroll
                for (int mt = 0; mt < 4; ++mt)
                    acc[mt][nt] = __builtin_amdgcn_mfma_f32_16x16x32_f16(
                        af[mt], bf, acc[mt][nt], 0, 0, 0);
            }
        };
        pf(afA, hvA, xsA, cBeg);
        for (int c = cBeg; c < cEnd; c += 2) {
            pf(afB, hvB, xsB, c + 1);
            cp(afA, hvA, xsA);
            if (c + 2 < cEnd) pf(afA, hvA, xsA, c + 2);
            cp(afB, hvB, xsB);
        }
    };

    // split-K exchange through LDS (f16, bank-rotated b128)
    auto xchg_write = [&]() {
#pragma unroll
        for (int cc = 0; cc < 8; ++cc) {
            int mt = cc >> 1, n0 = (cc & 1) * 2;
            half8 hv8;
#pragma unroll
            for (int r = 0; r < 4; ++r) {
                hv8[r]     = (_Float16)acc[mt][n0][r];
                hv8[4 + r] = (_Float16)acc[mt][n0 + 1][r];
            }
            int sl = (cc + lane) & 7;
            *(half8*)(xchg + bb * 4096 + lane * 64 + sl * 8) = hv8;
        }
    };
    auto xchg_read = [&]() {
#pragma unroll
        for (int cc = 0; cc < 8; ++cc) {
            int mt = cc >> 1, n0 = (cc & 1) * 2;
            int sl = (cc + lane) & 7;
            half8 hv8 = *(const half8*)(xchg + bb * 4096 + lane * 64 + sl * 8);
#pragma unroll
            for (int r = 0; r < 4; ++r) {
                acc[mt][n0][r]     += (float)hv8[r];
                acc[mt][n0 + 1][r] += (float)hv8[4 + r];
            }
        }
    };

    // S_l[b][i*fi+j] = sum_e x[i,e]*h[j,e]; this wave handles i-tile = ks
    auto sgemm = [&](const _Float16* hJ, int jp, int fi, _Float16* Sdst) {
        const _Float16* axp = sX + bb * 2048 + (ks * 16 + lr) * 64 + q * 8;
        const int njt = fi >> 4;
        for (int jt = 0; jt < njt; ++jt) {
            f32x4 sa = {0.0f, 0.0f, 0.0f, 0.0f};
#pragma unroll
            for (int c2 = 0; c2 < 2; ++c2) {
                half8 a = *(const half8*)(axp + c2 * 32);
                half8 b = *(const half8*)(hJ + (jt * 16 + lr) * jp + q * 8 + c2 * 32);
                sa = __builtin_amdgcn_mfma_f32_16x16x32_f16(a, b, sa, 0, 0, 0);
            }
#pragma unroll
            for (int r = 0; r < 4; ++r)
                Sdst[(size_t)batch * (32 * fi) + (ks * 16 + q * 4 + r) * fi
                     + jt * 16 + lr] = (_Float16)sa[r];
        }
    };

    // ---- phase 0 ----
    sgemm(sX + bb * 2048, 64, 32, S0);                 // S0 = x @ x^T
    kloop(Wt0, ks * 16, ks * 16 + 16, 0, slotA, 40);   // hidden rows 0..63
    if (ks == 1) xchg_write();
    __syncthreads();                                   // B1
    if (ks == 0) {
        xchg_read();
        // h1 = cur + bias: hT1 [e][j] -> slotB ; hJ1 [j][e] -> slotA
#pragma unroll
        for (int mt = 0; mt < 4; ++mt)
#pragma unroll
            for (int nt = 0; nt < 4; ++nt) {
                int e = nt * 16 + lr;
                int j = mt * 16 + q * 4;
                half4_ vh;
#pragma unroll
                for (int r = 0; r < 4; ++r) {
                    _Float16 hval = (_Float16)(acc[mt][nt][r] + bs0[j + r]);
                    vh[r] = hval;
                    slotA[bb * 4608 + (j + r) * 72 + e] = hval;
                }
                *(half4_*)(slotB + bb * 4608 + e * 72 + j) = vh;
            }
    }
    __syncthreads();                                   // B2

    // ---- phase 1 ----
    sgemm(slotA + bb * 4608, 72, 64, S1);              // S1 = x @ h1^T
    kloop(Wt1, ks * 32, ks * 32 + 32, 1, slotB, 72);   // hidden rows 0..63
    if (ks == 1) xchg_write();
    __syncthreads();                                   // B3
    if (ks == 0) {
        xchg_read();
        // h2 = cur + bias: only hJ2 [j][e] -> slotA (no per-e consumer left)
#pragma unroll
        for (int mt = 0; mt < 4; ++mt)
#pragma unroll
            for (int nt = 0; nt < 4; ++nt) {
                int e = nt * 16 + lr;
                int j = mt * 16 + q * 4;
#pragma unroll
                for (int r = 0; r < 4; ++r)
                    slotA[bb * 4608 + (j + r) * 72 + e]
                        = (_Float16)(acc[mt][nt][r] + bs1[j + r]);
            }
    }
    __syncthreads();                                   // B4

    sgemm(slotA + bb * 4608, 72, 64, S2);              // S2 = x @ h2^T
}

// Direct-output GEMM: out[b, ob+k] = S_l[b,:] . Wt_l[:, dm0+k] + 64*bias.
// 1024 waves: W<256 -> L0 (64 bt x 4 kt); <512 -> L1; else L2 (8 kt).
__global__ __launch_bounds__(256, 4)
void cin_direct(const _Float16* __restrict__ S0v, const _Float16* __restrict__ S1v,
                const _Float16* __restrict__ S2v,
                const _Float16* __restrict__ Wt0, const _Float16* __restrict__ Wt1,
                const _Float16* __restrict__ Wt2,
                const float* __restrict__ bs0, const float* __restrict__ bs1,
                const float* __restrict__ bs2,
                float* __restrict__ out)
{
    const int t = threadIdx.x, lane = t & 63;
    const int lr = lane & 15, q = lane >> 4;
    const int W = blockIdx.x * 4 + (t >> 6);

    const _Float16 *S, *Wt;
    const float* bias;
    int fan, nch, dm0, ob, idx;
    if (W < 256)      { S = S0v; Wt = Wt0; bias = bs0; fan = 1024; nch = 32; dm0 = 64; ob = 0;   idx = W; }
    else if (W < 512) { S = S1v; Wt = Wt1; bias = bs1; fan = 2048; nch = 64; dm0 = 64; ob = 64;  idx = W - 256; }
    else              { S = S2v; Wt = Wt2; bias = bs2; fan = 2048; nch = 64; dm0 = 0;  ob = 128; idx = W - 512; }
    const int bt = idx & 63, kt = idx >> 6;
    const int bbase = bt * 16;

    const _Float16* aG = Wt + (dm0 + kt * 16 + lr) * 32 + q * 8;   // + c*4096
    const _Float16* bG = S + (size_t)(bbase + lr) * fan + q * 8;   // + c*32

    f32x4 acc = {0.0f, 0.0f, 0.0f, 0.0f};
    half8 aA = *(const half8*)(aG);
    half8 bA = *(const half8*)(bG);
    for (int c = 0; c < nch; c += 2) {
        half8 aB = *(const half8*)(aG + (size_t)(c + 1) * 4096);
        half8 bB = *(const half8*)(bG + (c + 1) * 32);
        acc = __builtin_amdgcn_mfma_f32_16x16x32_f16(aA, bA, acc, 0, 0, 0);
        if (c + 2 < nch) {
            aA = *(const half8*)(aG + (size_t)(c + 2) * 4096);
            bA = *(const half8*)(bG + (c + 2) * 32);
        }
        acc = __builtin_amdgcn_mfma_f32_16x16x32_f16(aB, bB, acc, 0, 0, 0);
    }
#pragma unroll
    for (int r = 0; r < 4; ++r) {
        int kl = kt * 16 + q * 4 + r;
        out[(size_t)(bbase + lr) * 256 + ob + kl] = acc[r] + 64.0f * bias[dm0 + kl];
    }
}

extern "C" void kernel_launch(void* const* d_in, const int* in_sizes, int n_in,
                              void* d_out, int out_size, void* d_ws, size_t ws_size,
                              hipStream_t stream)
{
    const float* x  = (const float*)d_in[0];
    const float* W0 = (const float*)d_in[1];
    const float* b0 = (const float*)d_in[2];
    const float* W1 = (const float*)d_in[3];
    const float* b1 = (const float*)d_in[4];
    const float* W2 = (const float*)d_in[5];
    const float* b2 = (const float*)d_in[6];
    float* out = (float*)d_out;

    char* ws = (char*)d_ws;
    _Float16* Wt0 = (_Float16*)(ws + 0);           // 256 KB
    _Float16* Wt1 = (_Float16*)(ws + 262144);      // 512 KB
    _Float16* Wt2 = (_Float16*)(ws + 786432);      // 512 KB
    _Float16* S0  = (_Float16*)(ws + 1310720);     // 2 MB  (1024 x 1024 f16)
    _Float16* S1  = (_Float16*)(ws + 3407872);     // 4 MB  (1024 x 2048 f16)
    _Float16* S2  = (_Float16*)(ws + 7602176);     // 4 MB
    (void)in_sizes; (void)n_in; (void)out_size; (void)ws_size;

    hipLaunchKernelGGL(pack_w_all, dim3(160), dim3(256), 0, stream,
                       W0, Wt0, W1, Wt1, W2, Wt2);

    hipLaunchKernelGGL(cin_fused, dim3(512), dim3(256), 0, stream,
                       x, Wt0, Wt1, b0, b1, S0, S1, S2);

    hipLaunchKernelGGL(cin_direct, dim3(256), dim3(256), 0, stream,
                       S0, S1, S2, Wt0, Wt1, Wt2, b0, b1, b2, out);
}